// Round 4
// baseline (548.844 us; speedup 1.0000x reference)
//
#include <hip/hip_runtime.h>
#include <hip/hip_cooperative_groups.h>
#include <cstddef>

namespace cg = cooperative_groups;

#define NN 100000
#define EE 1600000
#define FF 128
#define BSH 9                        // 512 nodes per bucket
#define NB ((NN + 511) / 512)        // 196 buckets
#define EPB 4096                     // edges per binscatter block
#define NBLK 391                     // ceil(EE/EPB) — coop grid size

typedef unsigned int uint;
typedef unsigned short ushort;
typedef short short8 __attribute__((ext_vector_type(8)));
typedef float f32x4 __attribute__((ext_vector_type(4)));

__device__ __forceinline__ ushort f2bf(float f) {
  uint u = __float_as_uint(f);
  uint r = u + 0x7fffu + ((u >> 16) & 1u);   // RNE
  return (ushort)(r >> 16);
}
__device__ __forceinline__ uint pack2(float a, float b) {
  return (uint)f2bf(a) | ((uint)f2bf(b) << 16);
}
// accumulate 8 bf16 (one uint4) into 8 fp32
__device__ __forceinline__ void acc8(float* a, uint4 v) {
  a[0] += __uint_as_float(v.x << 16);
  a[1] += __uint_as_float(v.x & 0xffff0000u);
  a[2] += __uint_as_float(v.y << 16);
  a[3] += __uint_as_float(v.y & 0xffff0000u);
  a[4] += __uint_as_float(v.z << 16);
  a[5] += __uint_as_float(v.z & 0xffff0000u);
  a[6] += __uint_as_float(v.w << 16);
  a[7] += __uint_as_float(v.w & 0xffff0000u);
}

// =================== cooperative build_all ===================
// Phase A: x->bf16 + w0/w1 transpose-convert (grid-strided); block 0 zeroes btot
// Phase B: 196-bin bucket histogram (LDS-privatized)
// Phase C: scan bucket totals -> bbase/bcur (block 0)
// Phase D: binscatter (LDS counting-sort 4096 edges, coalesced dump)
// Phase E: fill2 (per-bucket node counts -> offsets + csr scatter)
__global__ __launch_bounds__(256) void build_all(
    const float4* __restrict__ x, uint4* __restrict__ xb,
    const float* __restrict__ w0, ushort* __restrict__ wt0,
    const float* __restrict__ w1, ushort* __restrict__ wt1,
    const int* __restrict__ ei, int* __restrict__ btot,
    int* __restrict__ bbase, int* __restrict__ bcur,
    int* __restrict__ offsets, uint2* __restrict__ pairs,
    int* __restrict__ csr)
{
  __shared__ union {
    struct { uint2 lpair[EPB]; int hcnt[256]; int hincl[256]; int hbase[256]; } bs; // 35 KB
    struct { int cnt[512]; int cur[512]; int s[256]; } f2;
    int sd[256];        // scan
    int h[256];         // hist
  } U;

  const int t = threadIdx.x;
  const int blk = blockIdx.x;
  const int gtid = blk * 256 + t;
  const int gstride = NBLK * 256;    // 100096
  cg::grid_group grid = cg::this_grid();

  // ---------------- Phase A: converts + btot zero ----------------
  if (blk == 0 && t < NB) btot[t] = 0;
  for (int i = gtid; i < NN * FF / 8; i += gstride) {
    float4 a = x[2 * i];
    float4 c = x[2 * i + 1];
    uint4 o;
    o.x = pack2(a.x, a.y);
    o.y = pack2(a.z, a.w);
    o.z = pack2(c.x, c.y);
    o.w = pack2(c.z, c.w);
    xb[i] = o;
  }
  for (int i = gtid; i < FF * FF; i += gstride) {
    int k = i >> 7, n = i & 127;
    wt0[n * FF + k] = f2bf(w0[(size_t)k * FF + n]);
    wt1[n * FF + k] = f2bf(w1[(size_t)k * FF + n]);
  }
  grid.sync();

  // ---------------- Phase B: bucket histogram ----------------
  {
    U.h[t] = 0;
    __syncthreads();
    const int e0 = blk * EPB + t;
#pragma unroll
    for (int i = 0; i < 16; ++i) {
      int e = e0 + i * 256;
      if (e < EE) atomicAdd(&U.h[ei[EE + e] >> BSH], 1);
    }
    __syncthreads();
    if (t < NB && U.h[t]) atomicAdd(&btot[t], U.h[t]);
  }
  grid.sync();

  // ---------------- Phase C: scan (block 0) ----------------
  if (blk == 0) {
    U.sd[t] = (t < NB) ? btot[t] : 0;
    __syncthreads();
    for (int off = 1; off < 256; off <<= 1) {
      int v = 0;
      if (t >= off) v = U.sd[t - off];
      __syncthreads();
      if (t >= off) U.sd[t] += v;
      __syncthreads();
    }
    if (t < NB) {
      int b = t ? U.sd[t - 1] : 0;
      bbase[t] = b;
      bcur[t] = b;
    }
    if (t == 0) {
      bbase[NB] = EE;
      offsets[NN] = EE;
    }
  }
  grid.sync();

  // ---------------- Phase D: binscatter ----------------
  {
    const int e0 = blk * EPB;
    U.bs.hcnt[t] = 0;
    __syncthreads();

    int es[16], ed[16];
#pragma unroll
    for (int i = 0; i < 16; ++i) {
      int e = e0 + t + i * 256;
      if (e < EE) {
        es[i] = ei[e];
        ed[i] = ei[EE + e];
        atomicAdd(&U.bs.hcnt[ed[i] >> BSH], 1);
      } else {
        es[i] = -1;
        ed[i] = 0;
      }
    }
    __syncthreads();

    const int mycnt = U.bs.hcnt[t];
    U.bs.hincl[t] = mycnt;
    __syncthreads();
    for (int off = 1; off < 256; off <<= 1) {
      int tv = 0;
      if (t >= off) tv = U.bs.hincl[t - off];
      __syncthreads();
      if (t >= off) U.bs.hincl[t] += tv;
      __syncthreads();
    }
    if (t < NB && mycnt > 0) U.bs.hbase[t] = atomicAdd(&bcur[t], mycnt);
    const int lbase = U.bs.hincl[t] - mycnt;
    __syncthreads();
    U.bs.hcnt[t] = lbase;            // becomes local scatter cursor
    __syncthreads();

#pragma unroll
    for (int i = 0; i < 16; ++i) {
      if (es[i] >= 0) {
        int b = ed[i] >> BSH;
        int pos = atomicAdd(&U.bs.hcnt[b], 1);
        U.bs.lpair[pos] = make_uint2((uint)es[i], (uint)ed[i]);
      }
    }
    __syncthreads();

    const int total = U.bs.hincl[255];
    for (int i = t; i < total; i += 256) {
      uint2 p = U.bs.lpair[i];
      int b = (int)(p.y >> BSH);     // bucket id directly from dst (no search)
      int lb = b ? U.bs.hincl[b - 1] : 0;
      pairs[(size_t)U.bs.hbase[b] + (i - lb)] = p;
    }
  }
  grid.sync();

  // ---------------- Phase E: fill2 (blocks < NB) ----------------
  if (blk < NB) {
    const int v0 = blk << BSH;
    U.f2.cnt[t] = 0;
    U.f2.cnt[t + 256] = 0;
    __syncthreads();
    const int pbeg = bbase[blk];
    const int pend = bbase[blk + 1];
    for (int j = pbeg + t; j < pend; j += 256)
      atomicAdd(&U.f2.cnt[(int)pairs[j].y - v0], 1);
    __syncthreads();
    const int c0 = U.f2.cnt[2 * t];
    const int c1 = U.f2.cnt[2 * t + 1];
    U.f2.s[t] = c0 + c1;
    __syncthreads();
    for (int off = 1; off < 256; off <<= 1) {
      int v = 0;
      if (t >= off) v = U.f2.s[t - off];
      __syncthreads();
      if (t >= off) U.f2.s[t] += v;
      __syncthreads();
    }
    const int base = t ? U.f2.s[t - 1] : 0;
    const int g0 = pbeg + base;
    const int g1 = g0 + c0;
    const int v = v0 + 2 * t;
    if (v < NN) offsets[v] = g0;
    if (v + 1 < NN) offsets[v + 1] = g1;
    U.f2.cur[2 * t] = g0;
    U.f2.cur[2 * t + 1] = g1;
    __syncthreads();
    for (int j = pbeg + t; j < pend; j += 256) {
      uint2 p = pairs[j];
      int pos = atomicAdd(&U.f2.cur[(int)p.y - v0], 1);
      csr[pos] = (int)p.x;
    }
  }
}

// ---------------- gather-reduce (bf16 rows -> bf16 rows) ----------------
// round-1 proven version: unroll-4, VGPR 24, occupancy ~69%
__global__ __launch_bounds__(256) void gather_bf16(const uint4* __restrict__ feat,
                                                   const int* __restrict__ offsets,
                                                   const int* __restrict__ csr,
                                                   ushort* __restrict__ out) {
  int t = blockIdx.x * 256 + threadIdx.x;
  int g = t >> 4;
  int l = t & 15;
  if (g >= NN) return;
  int beg = offsets[g];
  int end = offsets[g + 1];
  float acc[8] = {};
  acc8(acc, feat[(size_t)g * 16 + l]);           // self term
  int j = beg;
  for (; j + 4 <= end; j += 4) {
    int i0 = csr[j], i1 = csr[j + 1], i2 = csr[j + 2], i3 = csr[j + 3];
    uint4 v0 = feat[(size_t)i0 * 16 + l];
    uint4 v1 = feat[(size_t)i1 * 16 + l];
    uint4 v2 = feat[(size_t)i2 * 16 + l];
    uint4 v3 = feat[(size_t)i3 * 16 + l];
    acc8(acc, v0); acc8(acc, v1); acc8(acc, v2); acc8(acc, v3);
  }
  for (; j < end; ++j) acc8(acc, feat[(size_t)csr[j] * 16 + l]);
  uint4 o;
  o.x = pack2(acc[0], acc[1]);
  o.y = pack2(acc[2], acc[3]);
  o.z = pack2(acc[4], acc[5]);
  o.w = pack2(acc[6], acc[7]);
  ((uint4*)(out + (size_t)g * FF))[l] = o;
}

// ---------------- bf16 MFMA GEMM (no LDS) ----------------
template <bool BN, bool OUT16>
__global__ __launch_bounds__(256) void gemm_mfma(const ushort* __restrict__ a,
    const ushort* __restrict__ bt, const float* __restrict__ bias,
    const float* __restrict__ gamma, const float* __restrict__ beta,
    const float* __restrict__ rmean, const float* __restrict__ rvar,
    void* __restrict__ out0, int nrows)
{
  const int tid = threadIdx.x;
  const int wv = tid >> 6;
  const int l = tid & 63;
  const int lane16 = l & 15;
  const int quad = l >> 4;
  const int rowbase = blockIdx.x * 128 + wv * 32;

  f32x4 acc[2][8] = {};

  for (int kc = 0; kc < FF; kc += 32) {
    short8 af[2];
#pragma unroll
    for (int rt = 0; rt < 2; ++rt) {
      int r = min(rowbase + rt * 16 + lane16, nrows - 1);
      af[rt] = *(const short8*)(a + (size_t)r * FF + kc + quad * 8);
    }
#pragma unroll
    for (int ct = 0; ct < 8; ++ct) {
      int n = ct * 16 + lane16;
      short8 bf = *(const short8*)(bt + n * FF + kc + quad * 8);
      acc[0][ct] = __builtin_amdgcn_mfma_f32_16x16x32_bf16(af[0], bf, acc[0][ct], 0, 0, 0);
      acc[1][ct] = __builtin_amdgcn_mfma_f32_16x16x32_bf16(af[1], bf, acc[1][ct], 0, 0, 0);
    }
  }

  float sc[8], sh[8];
#pragma unroll
  for (int ct = 0; ct < 8; ++ct) {
    int c = ct * 16 + lane16;
    if (BN) {
      float s = gamma[c] * rsqrtf(rvar[c] + 1e-5f);
      sc[ct] = s;
      sh[ct] = (bias[c] - rmean[c]) * s + beta[c];
    } else {
      sc[ct] = 1.0f;
      sh[ct] = bias[c];
    }
  }

#pragma unroll
  for (int rt = 0; rt < 2; ++rt) {
#pragma unroll
    for (int reg = 0; reg < 4; ++reg) {
      int r = rowbase + rt * 16 + quad * 4 + reg;
      if (r < nrows) {
#pragma unroll
        for (int ct = 0; ct < 8; ++ct) {
          int c = ct * 16 + lane16;
          float v = fmaf(acc[rt][ct][reg], sc[ct], sh[ct]);
          if (BN) v = fmaxf(v, 0.0f);
          if (OUT16) ((ushort*)out0)[(size_t)r * FF + c] = f2bf(v);
          else       ((float*)out0)[(size_t)r * FF + c] = v;
        }
      }
    }
  }
}

extern "C" void kernel_launch(void* const* d_in, const int* in_sizes, int n_in,
                              void* d_out, int out_size, void* d_ws, size_t ws_size,
                              hipStream_t stream) {
  const float* x     = (const float*)d_in[0];
  const int*   ei    = (const int*)d_in[1];
  const float* w0    = (const float*)d_in[2];
  const float* b0    = (const float*)d_in[3];
  const float* gamma = (const float*)d_in[4];
  const float* beta  = (const float*)d_in[5];
  const float* rmean = (const float*)d_in[6];
  const float* rvar  = (const float*)d_in[7];
  const float* w1    = (const float*)d_in[8];
  const float* b1    = (const float*)d_in[9];
  float* out = (float*)d_out;

  // workspace layout
  ushort* sb  = (ushort*)d_ws;                    // NN*FF
  ushort* xb  = sb + (size_t)NN * FF;             // NN*FF
  ushort* hb  = xb + (size_t)NN * FF;             // NN*FF
  ushort* wt0 = hb + (size_t)NN * FF;             // 128*128
  ushort* wt1 = wt0 + FF * FF;                    // 128*128
  uint2* pairs  = (uint2*)(wt1 + FF * FF);        // EE uint2 (12.8 MB)
  int* csr      = (int*)(pairs + (size_t)EE);     // EE
  int* offsets  = csr + EE;                       // NN+1
  int* bcur     = offsets + NN + 1;               // NB
  int* bbase    = bcur + NB;                      // NB+1
  int* btot     = bbase + NB + 1;                 // NB

  const int gatherb = (NN * 16 + 255) / 256;      // 6250
  const int gemmb = (NN + 127) / 128;             // 782

  // ---- single cooperative dispatch: converts + full CSR build ----
  const float4* x4 = (const float4*)x;
  uint4* xb4 = (uint4*)xb;
  void* kargs[] = {
    (void*)&x4, (void*)&xb4, (void*)&w0, (void*)&wt0, (void*)&w1, (void*)&wt1,
    (void*)&ei, (void*)&btot, (void*)&bbase, (void*)&bcur, (void*)&offsets,
    (void*)&pairs, (void*)&csr
  };
  (void)hipLaunchCooperativeKernel((void*)build_all, dim3(NBLK), dim3(256),
                                   kargs, 0, stream);

  // ---- layer 1 ----
  gather_bf16<<<gatherb, 256, 0, stream>>>((const uint4*)xb, offsets, csr, sb);
  gemm_mfma<true, true><<<gemmb, 256, 0, stream>>>(sb, wt0, b0, gamma, beta,
                                                   rmean, rvar, (void*)hb, NN);
  // ---- layer 2 ----
  gather_bf16<<<gatherb, 256, 0, stream>>>((const uint4*)hb, offsets, csr, sb);
  gemm_mfma<false, false><<<gemmb, 256, 0, stream>>>(sb, wt1, b1, nullptr, nullptr,
                                                     nullptr, nullptr, (void*)out, NN);
}

// Round 5
// 357.526 us; speedup vs baseline: 1.5351x; 1.5351x over previous
//
#include <hip/hip_runtime.h>
#include <cstddef>

#define NN 100000
#define EE 1600000
#define FF 128
#define BSH 9                        // 512 nodes per bucket
#define NB ((NN + 511) / 512)        // 196 buckets
#define EPB 2048                     // edges per binscatter block (782 blocks)
#define HEPB 4096                    // edges per hist block (391 hist blocks)

typedef unsigned int uint;
typedef unsigned short ushort;
typedef short short8 __attribute__((ext_vector_type(8)));
typedef float f32x4 __attribute__((ext_vector_type(4)));

__device__ __forceinline__ ushort f2bf(float f) {
  uint u = __float_as_uint(f);
  uint r = u + 0x7fffu + ((u >> 16) & 1u);   // RNE
  return (ushort)(r >> 16);
}
__device__ __forceinline__ uint pack2(float a, float b) {
  return (uint)f2bf(a) | ((uint)f2bf(b) << 16);
}
// accumulate 8 bf16 (one uint4) into 8 fp32
__device__ __forceinline__ void acc8(float* a, uint4 v) {
  a[0] += __uint_as_float(v.x << 16);
  a[1] += __uint_as_float(v.x & 0xffff0000u);
  a[2] += __uint_as_float(v.y << 16);
  a[3] += __uint_as_float(v.y & 0xffff0000u);
  a[4] += __uint_as_float(v.z << 16);
  a[5] += __uint_as_float(v.z & 0xffff0000u);
  a[6] += __uint_as_float(v.w << 16);
  a[7] += __uint_as_float(v.w & 0xffff0000u);
}

// ---- fused converts + bucket histogram (heterogeneous grid) ----
// blocks 0..6249    : x -> bf16 (8 floats/thread)
// blocks 6250..6377 : w0/w1 fp32 [k][n] -> bf16 [n][k]
// blocks 6378..6768 : 196-bin bucket histogram (LDS-privatized), 4096 edges/blk
__global__ __launch_bounds__(256) void cvt_hist(const float4* __restrict__ x,
                                                uint4* __restrict__ xb,
                                                const float* __restrict__ w0,
                                                ushort* __restrict__ wt0,
                                                const float* __restrict__ w1,
                                                ushort* __restrict__ wt1,
                                                const int* __restrict__ ei,
                                                int* __restrict__ btot) {
  __shared__ int h[NB];
  const int b = blockIdx.x;
  const int t = threadIdx.x;
  if (b < 6250) {
    int i = b * 256 + t;
    if (i >= NN * FF / 8) return;
    float4 a = x[2 * i];
    float4 c = x[2 * i + 1];
    uint4 o;
    o.x = pack2(a.x, a.y);
    o.y = pack2(a.z, a.w);
    o.z = pack2(c.x, c.y);
    o.w = pack2(c.z, c.w);
    xb[i] = o;
  } else if (b < 6378) {
    int i = (b - 6250) * 256 + t;        // 0..32767
    const float* w = (i < 16384) ? w0 : w1;
    ushort* wt = (i < 16384) ? wt0 : wt1;
    int j = i & 16383;
    int k = j >> 7, n = j & 127;
    wt[n * FF + k] = f2bf(w[(size_t)k * FF + n]);
  } else {
    const int hb = b - 6378;             // 0..390
    for (int i = t; i < NB; i += 256) h[i] = 0;
    __syncthreads();
    const int e0 = hb * HEPB + t;
#pragma unroll
    for (int i = 0; i < 16; ++i) {
      int e = e0 + i * 256;
      if (e < EE) atomicAdd(&h[ei[EE + e] >> BSH], 1);
    }
    __syncthreads();
    for (int i = t; i < NB; i += 256)
      if (h[i]) atomicAdd(&btot[i], h[i]);
  }
}

// ---------------- scan 196 bucket totals -> bases (one block) ----------------
__global__ __launch_bounds__(256) void bucket_scan(const int* __restrict__ btot,
                                                   int* __restrict__ bbase,
                                                   int* __restrict__ bcur,
                                                   int* __restrict__ offsets) {
  __shared__ int sd[256];
  const int t = threadIdx.x;
  sd[t] = (t < NB) ? btot[t] : 0;
  __syncthreads();
  for (int off = 1; off < 256; off <<= 1) {
    int v = 0;
    if (t >= off) v = sd[t - off];
    __syncthreads();
    if (t >= off) sd[t] += v;
    __syncthreads();
  }
  if (t < NB) {
    int b = t ? sd[t - 1] : 0;
    bbase[t] = b;
    bcur[t] = b;
  }
  if (t == 0) {
    bbase[NB] = EE;
    offsets[NN] = EE;
  }
}

// ---- binscatter: LDS counting-sort 2048 edges by bucket, coalesced dump ----
// 782 blocks (2x concurrency vs 4096), 19 KB LDS, direct bucket-id dump
// (bucket recoverable from p.y >> BSH -> no per-element binary search).
__global__ __launch_bounds__(256) void binscatter(const int* __restrict__ ei,
                                                  int* __restrict__ bcur,
                                                  uint2* __restrict__ pairs) {
  __shared__ uint2 lpair[EPB];     // 16 KB
  __shared__ int hcnt[256];        // hist, then local scatter cursor
  __shared__ int hincl[256];       // inclusive scan over buckets
  __shared__ int hbase[256];       // global base per bucket
  const int t = threadIdx.x;
  const int e0 = blockIdx.x * EPB;

  hcnt[t] = 0;
  __syncthreads();

  int es[8], ed[8];
#pragma unroll
  for (int i = 0; i < 8; ++i) {
    int e = e0 + t + i * 256;
    if (e < EE) {
      es[i] = ei[e];
      ed[i] = ei[EE + e];
      atomicAdd(&hcnt[ed[i] >> BSH], 1);
    } else {
      es[i] = -1;
      ed[i] = 0;
    }
  }
  __syncthreads();

  const int mycnt = hcnt[t];
  hincl[t] = mycnt;
  __syncthreads();
  for (int off = 1; off < 256; off <<= 1) {
    int tv = 0;
    if (t >= off) tv = hincl[t - off];
    __syncthreads();
    if (t >= off) hincl[t] += tv;
    __syncthreads();
  }
  // reserve global range (one atomic per non-empty bucket per block)
  if (t < NB && mycnt > 0) hbase[t] = atomicAdd(&bcur[t], mycnt);
  const int lbase = hincl[t] - mycnt;
  __syncthreads();
  hcnt[t] = lbase;                 // becomes local scatter cursor
  __syncthreads();

#pragma unroll
  for (int i = 0; i < 8; ++i) {
    if (es[i] >= 0) {
      int b = ed[i] >> BSH;
      int pos = atomicAdd(&hcnt[b], 1);
      lpair[pos] = make_uint2((uint)es[i], (uint)ed[i]);
    }
  }
  __syncthreads();

  const int total = hincl[255];
  for (int i = t; i < total; i += 256) {
    uint2 p = lpair[i];
    int b = (int)(p.y >> BSH);     // bucket id directly from dst
    int lb = b ? hincl[b - 1] : 0;
    pairs[(size_t)hbase[b] + (i - lb)] = p;
  }
}

// ---- fill2: one block per bucket. Counts its 512 nodes in LDS, scans,
//      writes per-node offsets, then scatters csr with LDS cursors. ----
__global__ __launch_bounds__(512) void fill2(const uint2* __restrict__ pairs,
                                             const int* __restrict__ bbase,
                                             int* __restrict__ offsets,
                                             int* __restrict__ csr) {
  __shared__ int cnt[512];
  __shared__ int cur[512];
  const int t = threadIdx.x;
  const int b = blockIdx.x;
  const int v0 = b << BSH;
  cnt[t] = 0;
  __syncthreads();
  const int pbeg = bbase[b];
  const int pend = bbase[b + 1];
  for (int j = pbeg + t; j < pend; j += 512)
    atomicAdd(&cnt[(int)pairs[j].y - v0], 1);
  __syncthreads();
  const int my = cnt[t];
  cur[t] = my;
  __syncthreads();
  for (int off = 1; off < 512; off <<= 1) {
    int v = 0;
    if (t >= off) v = cur[t - off];
    __syncthreads();
    if (t >= off) cur[t] += v;
    __syncthreads();
  }
  const int goff = pbeg + cur[t] - my;
  const int v = v0 + t;
  if (v < NN) offsets[v] = goff;
  __syncthreads();
  cur[t] = goff;
  __syncthreads();
  for (int j = pbeg + t; j < pend; j += 512) {
    uint2 p = pairs[j];
    int pos = atomicAdd(&cur[(int)p.y - v0], 1);
    csr[pos] = (int)p.x;
  }
}

// ---------------- gather-reduce (bf16 rows -> bf16 rows) ----------------
// round-1 proven version: unroll-4, VGPR 24, occupancy ~69%
__global__ __launch_bounds__(256) void gather_bf16(const uint4* __restrict__ feat,
                                                   const int* __restrict__ offsets,
                                                   const int* __restrict__ csr,
                                                   ushort* __restrict__ out) {
  int t = blockIdx.x * 256 + threadIdx.x;
  int g = t >> 4;
  int l = t & 15;
  if (g >= NN) return;
  int beg = offsets[g];
  int end = offsets[g + 1];
  float acc[8] = {};
  acc8(acc, feat[(size_t)g * 16 + l]);           // self term
  int j = beg;
  for (; j + 4 <= end; j += 4) {
    int i0 = csr[j], i1 = csr[j + 1], i2 = csr[j + 2], i3 = csr[j + 3];
    uint4 v0 = feat[(size_t)i0 * 16 + l];
    uint4 v1 = feat[(size_t)i1 * 16 + l];
    uint4 v2 = feat[(size_t)i2 * 16 + l];
    uint4 v3 = feat[(size_t)i3 * 16 + l];
    acc8(acc, v0); acc8(acc, v1); acc8(acc, v2); acc8(acc, v3);
  }
  for (; j < end; ++j) acc8(acc, feat[(size_t)csr[j] * 16 + l]);
  uint4 o;
  o.x = pack2(acc[0], acc[1]);
  o.y = pack2(acc[2], acc[3]);
  o.z = pack2(acc[4], acc[5]);
  o.w = pack2(acc[6], acc[7]);
  ((uint4*)(out + (size_t)g * FF))[l] = o;
}

// ---------------- bf16 MFMA GEMM (no LDS) ----------------
template <bool BN, bool OUT16>
__global__ __launch_bounds__(256) void gemm_mfma(const ushort* __restrict__ a,
    const ushort* __restrict__ bt, const float* __restrict__ bias,
    const float* __restrict__ gamma, const float* __restrict__ beta,
    const float* __restrict__ rmean, const float* __restrict__ rvar,
    void* __restrict__ out0, int nrows)
{
  const int tid = threadIdx.x;
  const int wv = tid >> 6;
  const int l = tid & 63;
  const int lane16 = l & 15;
  const int quad = l >> 4;
  const int rowbase = blockIdx.x * 128 + wv * 32;

  f32x4 acc[2][8] = {};

  for (int kc = 0; kc < FF; kc += 32) {
    short8 af[2];
#pragma unroll
    for (int rt = 0; rt < 2; ++rt) {
      int r = min(rowbase + rt * 16 + lane16, nrows - 1);
      af[rt] = *(const short8*)(a + (size_t)r * FF + kc + quad * 8);
    }
#pragma unroll
    for (int ct = 0; ct < 8; ++ct) {
      int n = ct * 16 + lane16;
      short8 bf = *(const short8*)(bt + n * FF + kc + quad * 8);
      acc[0][ct] = __builtin_amdgcn_mfma_f32_16x16x32_bf16(af[0], bf, acc[0][ct], 0, 0, 0);
      acc[1][ct] = __builtin_amdgcn_mfma_f32_16x16x32_bf16(af[1], bf, acc[1][ct], 0, 0, 0);
    }
  }

  float sc[8], sh[8];
#pragma unroll
  for (int ct = 0; ct < 8; ++ct) {
    int c = ct * 16 + lane16;
    if (BN) {
      float s = gamma[c] * rsqrtf(rvar[c] + 1e-5f);
      sc[ct] = s;
      sh[ct] = (bias[c] - rmean[c]) * s + beta[c];
    } else {
      sc[ct] = 1.0f;
      sh[ct] = bias[c];
    }
  }

#pragma unroll
  for (int rt = 0; rt < 2; ++rt) {
#pragma unroll
    for (int reg = 0; reg < 4; ++reg) {
      int r = rowbase + rt * 16 + quad * 4 + reg;
      if (r < nrows) {
#pragma unroll
        for (int ct = 0; ct < 8; ++ct) {
          int c = ct * 16 + lane16;
          float v = fmaf(acc[rt][ct][reg], sc[ct], sh[ct]);
          if (BN) v = fmaxf(v, 0.0f);
          if (OUT16) ((ushort*)out0)[(size_t)r * FF + c] = f2bf(v);
          else       ((float*)out0)[(size_t)r * FF + c] = v;
        }
      }
    }
  }
}

extern "C" void kernel_launch(void* const* d_in, const int* in_sizes, int n_in,
                              void* d_out, int out_size, void* d_ws, size_t ws_size,
                              hipStream_t stream) {
  const float* x     = (const float*)d_in[0];
  const int*   ei    = (const int*)d_in[1];
  const float* w0    = (const float*)d_in[2];
  const float* b0    = (const float*)d_in[3];
  const float* gamma = (const float*)d_in[4];
  const float* beta  = (const float*)d_in[5];
  const float* rmean = (const float*)d_in[6];
  const float* rvar  = (const float*)d_in[7];
  const float* w1    = (const float*)d_in[8];
  const float* b1    = (const float*)d_in[9];
  float* out = (float*)d_out;

  // workspace layout
  ushort* sb  = (ushort*)d_ws;                    // NN*FF
  ushort* xb  = sb + (size_t)NN * FF;             // NN*FF
  ushort* hb  = xb + (size_t)NN * FF;             // NN*FF
  ushort* wt0 = hb + (size_t)NN * FF;             // 128*128
  ushort* wt1 = wt0 + FF * FF;                    // 128*128
  uint2* pairs  = (uint2*)(wt1 + FF * FF);        // EE uint2 (12.8 MB)
  int* csr      = (int*)(pairs + (size_t)EE);     // EE
  int* offsets  = csr + EE;                       // NN+1
  int* bcur     = offsets + NN + 1;               // NB
  int* bbase    = bcur + NB;                      // NB+1
  int* btot     = bbase + NB + 1;                 // NB

  const int gatherb = (NN * 16 + 255) / 256;      // 6250
  const int gemmb = (NN + 127) / 128;             // 782
  const int binb = (EE + EPB - 1) / EPB;          // 782
  const int cvb = 6250 + 128 + 391;               // 6769

  // ---- converts + hist (fused), then CSR build ----
  (void)hipMemsetAsync(btot, 0, (size_t)NB * sizeof(int), stream);
  cvt_hist<<<cvb, 256, 0, stream>>>((const float4*)x, (uint4*)xb, w0, wt0,
                                    w1, wt1, ei, btot);
  bucket_scan<<<1, 256, 0, stream>>>(btot, bbase, bcur, offsets);
  binscatter<<<binb, 256, 0, stream>>>(ei, bcur, pairs);
  fill2<<<NB, 512, 0, stream>>>(pairs, bbase, offsets, csr);

  // ---- layer 1 ----
  gather_bf16<<<gatherb, 256, 0, stream>>>((const uint4*)xb, offsets, csr, sb);
  gemm_mfma<true, true><<<gemmb, 256, 0, stream>>>(sb, wt0, b0, gamma, beta,
                                                   rmean, rvar, (void*)hb, NN);
  // ---- layer 2 ----
  gather_bf16<<<gatherb, 256, 0, stream>>>((const uint4*)hb, offsets, csr, sb);
  gemm_mfma<false, false><<<gemmb, 256, 0, stream>>>(sb, wt1, b1, nullptr, nullptr,
                                                     nullptr, nullptr, (void*)out, NN);
}